// Round 8
// baseline (8902.235 us; speedup 1.0000x reference)
//
#include <hip/hip_runtime.h>
#include <hip/hip_fp16.h>
#include <cstdint>
#include <cstddef>

#define EPSF 2.220446049250313e-16f

// Sizes (fixed by the problem)
#define Bn   64
#define TP2n 1024
#define Tn   1023
#define Hn   256
#define H7n  1792
#define Kn   128
#define NEn  131

// k_scan row split per block: 255 rows in LDS (130,560B), 193 streamed from L2
#define LROWS 255

typedef _Float16 f16x2 __attribute__((ext_vector_type(2)));

__device__ __forceinline__ f16x2 u2h(unsigned u) { return __builtin_bit_cast(f16x2, u); }
__device__ __forceinline__ f16x2 f2h(float f)    { return __builtin_bit_cast(f16x2, f); }

__device__ __forceinline__ float fdot2f(f16x2 a, f16x2 b, float c) {
#if __has_builtin(__builtin_amdgcn_fdot2)
  return __builtin_amdgcn_fdot2(a, b, c, false);
#else
  return c + (float)a[0] * (float)b[0] + (float)a[1] * (float)b[1];
#endif
}

__device__ __forceinline__ float sigmf(float x) { return 1.f / (1.f + __expf(-x)); }

__device__ __forceinline__ float tanhfast(float x) {
  float t = __expf(2.f * fabsf(x));        // inf-safe: t=inf -> r=1
  float r = 1.f - 2.f / (t + 1.f);
  return copysignf(r, x);
}

__device__ __forceinline__ float softplusf(float x) {
  return fmaxf(x, 0.f) + log1pf(__expf(-fabsf(x)));
}

// ---------------------------------------------------------------------------
// EW[e][r] = b[r] + sum_k Emb[e][k] * W[r][k]   (input half of W, k<256)
__global__ void k_ew(const float* __restrict__ Emb, const float* __restrict__ W,
                     const float* __restrict__ bvec, float* __restrict__ EW) {
  int e = blockIdx.x;  // 0..130
  __shared__ float es[Hn];
  for (int k = threadIdx.x; k < Hn; k += blockDim.x) es[k] = Emb[e * Hn + k];
  __syncthreads();
  for (int r = threadIdx.x; r < H7n; r += blockDim.x) {
    const float* wr = W + (size_t)r * (2 * Hn);
    float acc = bvec[r];
#pragma unroll 4
    for (int k = 0; k < Hn; ++k) acc += es[k] * wr[k];
    EW[e * H7n + r] = acc;
  }
}

// ---------------------------------------------------------------------------
// Recurrent weights fp16, ROW-CONTIGUOUS (512B per row):
// wt3[r*128 + k2] = half2(W[r][256+2k2], W[r][256+2k2+1])
__global__ void k_wt(const float* __restrict__ W, unsigned* __restrict__ wt3) {
  int gid = blockIdx.x * blockDim.x + threadIdx.x;
  if (gid >= H7n * 128) return;
  int r = gid >> 7, k2 = gid & 127;
  const float* p = W + (size_t)r * 512 + 256 + 2 * k2;
  f16x2 v; v[0] = (_Float16)p[0]; v[1] = (_Float16)p[1];
  wt3[gid] = __builtin_bit_cast(unsigned, v);
}

// ---------------------------------------------------------------------------
__global__ void k_init(float* __restrict__ acc, int* __restrict__ flags) {
  int i = threadIdx.x;  // 1024 threads
  if (i < 192) acc[i] = 0.f;  // lam_acc[64], mask_acc[64], loglik_sum[64]
  flags[i] = 0;               // 64 batches x 16 ints (64B padded)
}

// ---------------------------------------------------------------------------
// Sequential CT-LSTM scan, 4 blocks per batch, 448 threads, 1 z-row/thread.
//
// WEIGHT RESIDENCY (rounds 3-7 post-mortem): the compiler refuses to keep a
// 128-VGPR weight array live across the t-loop (always spills/sinks; VGPR=84
// every time) -> per-CU re-ingest of 229KB/step through the ~134GB/s L1 fill
// path was the 5.6us/step floor. Fix: HYBRID residency.
//   rows 0..254   (of this block's 448): fp16 weights in LDS, loaded once.
//                 LDS = 255*512B = 130,560B + h4(512B) = 131,072B total
//                 (m201 precedent: 128KiB static LDS compiles on gfx950).
//                 16B-slot XOR swizzle by (row&31): without it, the 512B row
//                 stride puts all 64 lanes on the same 4 banks (16+-way
//                 conflict); with it, 32 distinct slots -> conflict-free.
//   rows 255..447: streamed from L2 per step (98.8KB/CU/step, vector-mem
//                 pipe, overlaps the LDS-path waves).
// ev_s/dt_s LDS staging dropped (frees LDS): event/dtime are uniform scalar
// loads prefetched one step ahead.
//
// Per step: local 448-row z-slice -> global z exchange with one flag
// handshake (agent atomics, parity double-buffer; relaxed polls + single
// acquire fence) -> redundant elementwise recurrence (c/cb in regs, h in
// LDS). Role 0 stores the packed state.
__global__ __launch_bounds__(448) void k_scan(
    const int* __restrict__ event, const float* __restrict__ dtime,
    const float* __restrict__ EW, const unsigned* __restrict__ wt3,
    float* __restrict__ zx, int* __restrict__ flags,
    uint2* __restrict__ state) {
  const int x = blockIdx.x;
  // co-locate a batch's 4 blocks on one XCD (assuming xcd = blockIdx % 8);
  // correctness does not depend on this mapping, only L2 locality.
  const int xcd = x & 7, q = x >> 3;
  const int b = xcd * 8 + (q >> 2);
  const int role = q & 3;
  const int tid = threadIdx.x;
  const int row = role * 448 + tid;

  __shared__ uint4  wlds[LROWS * 32];  // 130,560B swizzled fp16 weights
  __shared__ float4 h4[Hn / 8];        // 512B: 256 halves of h

  const uint4* wt4 = reinterpret_cast<const uint4*>(wt3);  // [r*32 + k8]

  // ---- one-time LDS weight fill (swizzled) ----
  for (int i = tid; i < LROWS * 32; i += 448) {
    int lr = i >> 5, k8 = i & 31;
    wlds[lr * 32 + (k8 ^ (lr & 31))] =
        wt4[((size_t)role * 448 + lr) * 32 + k8];
  }
  if (tid < Hn / 8) h4[tid] = make_float4(0.f, 0.f, 0.f, 0.f);
  __syncthreads();

  float c_r = 0.f, cb_r = 0.f;      // replicated recurrent state (tid<256)
  int* flg = flags + b * 16;

  // uniform scalar prefetch chain for event/dtime (one step of slack each)
  const int*   evp = event + (size_t)b * TP2n;
  const float* dtp = dtime + (size_t)b * TP2n;
  int   e_c  = evp[0];
  float ew_pf = EW[(size_t)e_c * H7n + row];
  int   e_n  = evp[1];
  float dt_c = dtp[1];

  for (int t = 0; t < Tn; ++t) {
    const int par = t & 1;
    float ewc = ew_pf;
    ew_pf = EW[(size_t)e_n * H7n + row];   // EW row for step t+1
    int idx2 = (t + 2 <= Tn) ? (t + 2) : Tn;
    int   e_n2 = evp[idx2];
    float dt_n = dtp[idx2];

    // ---- z for this thread's row (4 independent dot chains) ----
    float a0 = ewc, a1 = 0.f, a2 = 0.f, a3 = 0.f;
    if (tid < LROWS) {
      const uint4* wp = wlds + tid * 32;
      const int sw = tid & 31;
#pragma unroll
      for (int k8 = 0; k8 < 32; ++k8) {
        float4 hq = h4[k8];              // uniform-address broadcast read
        uint4 ww = wp[k8 ^ sw];
        a0 = fdot2f(u2h(ww.x), f2h(hq.x), a0);
        a1 = fdot2f(u2h(ww.y), f2h(hq.y), a1);
        a2 = fdot2f(u2h(ww.z), f2h(hq.z), a2);
        a3 = fdot2f(u2h(ww.w), f2h(hq.w), a3);
      }
    } else {
      const uint4* wp = wt4 + (size_t)row * 32;
#pragma unroll
      for (int k8 = 0; k8 < 32; ++k8) {
        float4 hq = h4[k8];
        uint4 ww = wp[k8];               // L2-resident re-stream (intended)
        a0 = fdot2f(u2h(ww.x), f2h(hq.x), a0);
        a1 = fdot2f(u2h(ww.y), f2h(hq.y), a1);
        a2 = fdot2f(u2h(ww.z), f2h(hq.z), a2);
        a3 = fdot2f(u2h(ww.w), f2h(hq.w), a3);
      }
    }
    float z = (a0 + a1) + (a2 + a3);

    // ---- exchange: write slice, one flag handshake ----
    float* zb = zx + ((size_t)b * 2 + par) * H7n;
    __hip_atomic_store(zb + row, z, __ATOMIC_RELAXED, __HIP_MEMORY_SCOPE_AGENT);
    __syncthreads();                 // drains vmcnt: all block stores visible
    if (tid == 0)
      __hip_atomic_store(flg + role, t + 1, __ATOMIC_RELEASE,
                         __HIP_MEMORY_SCOPE_AGENT);
    if (tid < 4) {
      // relaxed polls (no per-poll L1 invalidate), single acquire fence after
      while (__hip_atomic_load(flg + tid, __ATOMIC_RELAXED,
                               __HIP_MEMORY_SCOPE_AGENT) <= t) {}
      __builtin_amdgcn_fence(__ATOMIC_ACQUIRE, "agent");
    }
    __syncthreads();

    // ---- elementwise recurrence, replicated (threads 0..255) ----
    if (tid < Hn) {
      const int j = tid;
      float zg[7];
#pragma unroll
      for (int g = 0; g < 7; ++g)
        zg[g] = __hip_atomic_load(zb + g * Hn + j, __ATOMIC_RELAXED,
                                  __HIP_MEMORY_SCOPE_AGENT);
      float gi  = sigmf(zg[0]);
      float gf  = sigmf(zg[1]);
      float go  = sigmf(zg[2]);
      float zc  = tanhfast(zg[3]);
      float gib = sigmf(zg[4]);
      float gfb = sigmf(zg[5]);
      float gd  = softplusf(zg[6]);
      float ci  = gf * c_r + gi * zc;
      float cbi = gfb * cb_r + gib * zc;
      float cn  = cbi + (ci - cbi) * __expf(-gd * dt_c);
      float hn  = go * tanhfast(cn);
      c_r = cn; cb_r = cbi;
      reinterpret_cast<__half*>(h4)[j] = __float2half(hn);
      if (role == 0) {
        f16x2 p0; p0[0] = (_Float16)ci; p0[1] = (_Float16)cbi;
        f16x2 p1; p1[0] = (_Float16)gd; p1[1] = (_Float16)go;
        uint2 o;
        o.x = __builtin_bit_cast(unsigned, p0);
        o.y = __builtin_bit_cast(unsigned, p1);
        state[((size_t)b * Tn + t) * Hn + j] = o;
      }
    }
    __syncthreads();
    e_n = e_n2; dt_c = dt_n;
  }
}

// ---------------------------------------------------------------------------
// log_lam_tgt, fully parallel: one wave per (b,t). Recomputes h_next from the
// packed state (same formula as sampling with dt = dtime[t+1]).
__global__ __launch_bounds__(256) void k_post(
    const uint2* __restrict__ state, const int* __restrict__ event,
    const float* __restrict__ dtime, const float* __restrict__ Wl,
    float* __restrict__ loglik_sum) {
  const int wid = blockIdx.x * 4 + (threadIdx.x >> 6);  // 0..65471
  const int lane = threadIdx.x & 63;
  const int b = wid / Tn;
  const int t = wid - b * Tn;
  const int tgt = event[b * TP2n + t + 1];
  if (tgt >= Kn) return;                                 // wave-uniform
  const float dtv = dtime[b * TP2n + t + 1];
  const uint2* srow = state + (size_t)wid * Hn;
  uint4 sA = *reinterpret_cast<const uint4*>(srow + lane * 4);
  uint4 sB = *reinterpret_cast<const uint4*>(srow + lane * 4 + 2);
  float4 wl = *reinterpret_cast<const float4*>(Wl + tgt * Hn + lane * 4);
  float h[4];
#pragma unroll
  for (int qq = 0; qq < 4; ++qq) {
    unsigned lo = (qq == 0) ? sA.x : (qq == 1) ? sA.z : (qq == 2) ? sB.x : sB.z;
    unsigned hi = (qq == 0) ? sA.y : (qq == 1) ? sA.w : (qq == 2) ? sB.y : sB.w;
    f16x2 p0 = u2h(lo), p1 = u2h(hi);
    float c = p0[0], cb = p0[1], gd = p1[0], go = p1[1];
    float cs = cb + (c - cb) * __expf(-gd * dtv);
    h[qq] = go * tanhfast(cs);
  }
  float d = h[0] * wl.x + h[1] * wl.y + h[2] * wl.z + h[3] * wl.w;
#pragma unroll
  for (int off = 32; off; off >>= 1) d += __shfl_down(d, off);
  if (lane == 0) atomicAdd(&loglik_sum[b], __logf(softplusf(d) + EPSF));
}

// ---------------------------------------------------------------------------
// Sampling: 1024 blocks (16/batch, 64 samples each) x 128 threads; thread k
// holds Wl row k in registers. Packed-state gather (one uint4/thread),
// next-sample prefetch.
__global__ __launch_bounds__(128) void k_samp(
    const uint2* __restrict__ state, const float* __restrict__ Wl,
    const int* __restrict__ sidx, const float* __restrict__ sdt,
    const float* __restrict__ smask,
    float* __restrict__ lam_acc, float* __restrict__ mask_acc) {
  const int blk = blockIdx.x;
  const int b = blk >> 4;
  const int base = (b << 10) + (blk & 15) * 64;
  const int tid = threadIdx.x;

  f16x2 wr[128];
  {
    const float* wrow = Wl + tid * Hn;
#pragma unroll
    for (int i = 0; i < 128; ++i) {
      f16x2 v; v[0] = (_Float16)wrow[2 * i]; v[1] = (_Float16)wrow[2 * i + 1];
      wr[i] = v;
    }
  }
  __shared__ float4 hy4[Hn / 8];
  __shared__ float  red[2];
  float accl = 0.f, accm = 0.f;

  int   row = sidx[base];
  float dtv = sdt[base];
  float mk  = smask[base];
  uint4 st = *reinterpret_cast<const uint4*>(state + (size_t)row * Hn + 2 * tid);

  for (int s = 0; s < 64; ++s) {
    f16x2 p0 = u2h(st.x), p1 = u2h(st.y);
    f16x2 q0 = u2h(st.z), q1 = u2h(st.w);
    float cs0 = (float)p0[1] + ((float)p0[0] - (float)p0[1]) * __expf(-(float)p1[0] * dtv);
    float cs1 = (float)q0[1] + ((float)q0[0] - (float)q0[1]) * __expf(-(float)q1[0] * dtv);
    f16x2 hp;
    hp[0] = (_Float16)((float)p1[1] * tanhfast(cs0));
    hp[1] = (_Float16)((float)q1[1] * tanhfast(cs1));
    reinterpret_cast<unsigned*>(hy4)[tid] = __builtin_bit_cast(unsigned, hp);

    uint4 st_n = st; float dt_n = dtv, mk_n = mk;
    if (s < 63) {
      int sg = base + s + 1;
      int r2 = sidx[sg];
      dt_n = sdt[sg];
      mk_n = smask[sg];
      st_n = *reinterpret_cast<const uint4*>(state + (size_t)r2 * Hn + 2 * tid);
    }
    __syncthreads();

    float d = 0.f;
#pragma unroll
    for (int q = 0; q < 32; ++q) {
      float4 hq = hy4[q];
      d = fdot2f(wr[4 * q + 0], f2h(hq.x), d);
      d = fdot2f(wr[4 * q + 1], f2h(hq.y), d);
      d = fdot2f(wr[4 * q + 2], f2h(hq.z), d);
      d = fdot2f(wr[4 * q + 3], f2h(hq.w), d);
    }
    float lam = softplusf(d);
#pragma unroll
    for (int off = 32; off; off >>= 1) lam += __shfl_down(lam, off);
    if ((tid & 63) == 0) red[tid >> 6] = lam;
    __syncthreads();
    if (tid == 0) {
      accl += (red[0] + red[1]) * mk;
      accm += mk;
    }
    st = st_n; dtv = dt_n; mk = mk_n;
  }
  if (tid == 0) {
    atomicAdd(&lam_acc[b], accl);
    atomicAdd(&mask_acc[b], accm);
  }
}

// ---------------------------------------------------------------------------
__global__ void k_final(const float* __restrict__ loglik_sum,
                        const float* __restrict__ lam_acc,
                        const float* __restrict__ mask_acc,
                        const float* __restrict__ duration,
                        float* __restrict__ out) {
  int b = threadIdx.x;
  if (b < Bn) out[b] = loglik_sum[b] - (lam_acc[b] / mask_acc[b]) * duration[b];
}

// ---------------------------------------------------------------------------
extern "C" void kernel_launch(void* const* d_in, const int* in_sizes, int n_in,
                              void* d_out, int out_size, void* d_ws, size_t ws_size,
                              hipStream_t stream) {
  const int*   event    = (const int*)d_in[0];
  const float* dtime    = (const float*)d_in[1];
  const float* duration = (const float*)d_in[3];
  const float* sdt      = (const float*)d_in[4];
  const int*   sidx     = (const int*)d_in[5];
  const float* smask    = (const float*)d_in[6];
  const float* Emb      = (const float*)d_in[7];
  const float* W        = (const float*)d_in[8];
  const float* bv       = (const float*)d_in[9];
  const float* Wl       = (const float*)d_in[10];

  char* ws = (char*)d_ws;
  // layout: EW(0.94MB)@0 | wt3(0.92MB)@1MB | acc+flags@2MB | zx(0.92MB)@3MB |
  //         packed state(134MB)@4MB
  float* EW         = (float*)(ws + 0);
  unsigned* wt3     = (unsigned*)(ws + (1u << 20));
  float* lam_acc    = (float*)(ws + (2u << 20));
  float* mask_acc   = lam_acc + 64;
  float* loglik_sum = lam_acc + 128;
  int*   flags      = (int*)(ws + (2u << 20) + 4096);
  float* zx         = (float*)(ws + (3u << 20));
  uint2* state      = (uint2*)(ws + (4u << 20));

  k_ew<<<dim3(NEn), dim3(256), 0, stream>>>(Emb, W, bv, EW);
  k_wt<<<dim3(896), dim3(256), 0, stream>>>(W, wt3);
  k_init<<<dim3(1), dim3(1024), 0, stream>>>(lam_acc, flags);
  k_scan<<<dim3(256), dim3(448), 0, stream>>>(event, dtime, EW, wt3, zx,
                                              flags, state);
  k_post<<<dim3(16368), dim3(256), 0, stream>>>(state, event, dtime, Wl,
                                                loglik_sum);
  k_samp<<<dim3(1024), dim3(128), 0, stream>>>(state, Wl, sidx, sdt, smask,
                                               lam_acc, mask_acc);
  k_final<<<dim3(1), dim3(64), 0, stream>>>(loglik_sum, lam_acc, mask_acc,
                                            duration, (float*)d_out);
}

// Round 9
// 6265.482 us; speedup vs baseline: 1.4208x; 1.4208x over previous
//
#include <hip/hip_runtime.h>
#include <hip/hip_fp16.h>
#include <cstdint>
#include <cstddef>

#define EPSF 2.220446049250313e-16f

// Sizes (fixed by the problem)
#define Bn   64
#define TP2n 1024
#define Tn   1023
#define Hn   256
#define H7n  1792
#define Kn   128
#define NEn  131

typedef _Float16 f16x2 __attribute__((ext_vector_type(2)));

__device__ __forceinline__ f16x2 u2h(unsigned u) { return __builtin_bit_cast(f16x2, u); }
__device__ __forceinline__ f16x2 f2h(float f)    { return __builtin_bit_cast(f16x2, f); }

__device__ __forceinline__ float fdot2f(f16x2 a, f16x2 b, float c) {
#if __has_builtin(__builtin_amdgcn_fdot2)
  return __builtin_amdgcn_fdot2(a, b, c, false);
#else
  return c + (float)a[0] * (float)b[0] + (float)a[1] * (float)b[1];
#endif
}

__device__ __forceinline__ float sigmf(float x) { return 1.f / (1.f + __expf(-x)); }

__device__ __forceinline__ float tanhfast(float x) {
  float t = __expf(2.f * fabsf(x));        // inf-safe: t=inf -> r=1
  float r = 1.f - 2.f / (t + 1.f);
  return copysignf(r, x);
}

__device__ __forceinline__ float softplusf(float x) {
  return fmaxf(x, 0.f) + log1pf(__expf(-fabsf(x)));
}

// fp8-e4m3 pair decode: u32 packed as bytes (b0,b2,b1,b3).
// e4m3 -> f16 is exact modulo x2^8 (folded into the per-row scale):
// f16bits(b) = ((b&0x7f)<<7) | (sign<<15), value = true/2^8 (denorms incl).
__device__ __forceinline__ void dec_dot2(unsigned x, float hp0, float hp1,
                                         float& accA, float& accB) {
  unsigned f0 = ((x & 0x007f007fu) << 7) | ((x & 0x00800080u) << 8);
  unsigned f1 = ((x & 0x7f007f00u) >> 1) | (x & 0x80008000u);
  accA = fdot2f(u2h(f0), f2h(hp0), accA);
  accB = fdot2f(u2h(f1), f2h(hp1), accB);
}

// ---------------------------------------------------------------------------
// EW[e][r] = b[r] + sum_k Emb[e][k] * W[r][k]   (input half of W, k<256)
__global__ void k_ew(const float* __restrict__ Emb, const float* __restrict__ W,
                     const float* __restrict__ bvec, float* __restrict__ EW) {
  int e = blockIdx.x;  // 0..130
  __shared__ float es[Hn];
  for (int k = threadIdx.x; k < Hn; k += blockDim.x) es[k] = Emb[e * Hn + k];
  __syncthreads();
  for (int r = threadIdx.x; r < H7n; r += blockDim.x) {
    const float* wr = W + (size_t)r * (2 * Hn);
    float acc = bvec[r];
#pragma unroll 4
    for (int k = 0; k < Hn; ++k) acc += es[k] * wr[k];
    EW[e * H7n + r] = acc;
  }
}

// ---------------------------------------------------------------------------
// Quantize recurrent weights to fp8-e4m3 with per-row scale (s_r = max/448).
// One wave per row. Output word j of row r = bytes (q[4j],q[4j+2],q[4j+1],
// q[4j+3]) so the scan's pair-decode is pure masks. sc[r] = s_r * 256.
__global__ __launch_bounds__(64) void k_wq(const float* __restrict__ W,
                                           unsigned* __restrict__ wq,
                                           float* __restrict__ sc) {
  const int r = blockIdx.x;           // 0..1791
  const int j = threadIdx.x;          // 0..63
  const float* wr = W + (size_t)r * 512 + 256;
  float4 wv = *reinterpret_cast<const float4*>(wr + 4 * j);
  float m = fmaxf(fmaxf(fabsf(wv.x), fabsf(wv.y)),
                  fmaxf(fabsf(wv.z), fabsf(wv.w)));
#pragma unroll
  for (int off = 32; off; off >>= 1) m = fmaxf(m, __shfl_xor(m, off));
  float inv_s = (m > 0.f) ? 448.f / m : 0.f;
  float v[4] = {wv.x, wv.y, wv.z, wv.w};
  unsigned b[4];
#pragma unroll
  for (int q = 0; q < 4; ++q) {
    float ay = fabsf(v[q]) * inv_s;     // in [0, 448]
    unsigned byte;
    if (ay < 0.015625f) {               // < 2^-6: denorm m*2^-9 (RNE, rollover ok)
      byte = (unsigned)(int)rintf(ay * 512.f);
    } else {                            // normal: rebias to 7, RNE to 3-bit mantissa
      unsigned ub = __builtin_bit_cast(unsigned, ay);
      unsigned E  = (ub >> 23) & 255u;
      unsigned vv = ((E - 120u) << 23) | (ub & 0x7fffffu);
      byte = (vv + 0x7ffffu + ((vv >> 20) & 1u)) >> 20;
      if (byte > 0x7eu) byte = 0x7eu;   // clamp at 448
    }
    if (v[q] < 0.f) byte |= 0x80u;
    b[q] = byte;
  }
  wq[(size_t)r * 64 + j] = b[0] | (b[2] << 8) | (b[1] << 16) | (b[3] << 24);
  if (j == 0) sc[r] = (m / 448.f) * 256.f;
}

// ---------------------------------------------------------------------------
__global__ void k_init(float* __restrict__ acc, int* __restrict__ flags) {
  int i = threadIdx.x;  // 1024 threads
  if (i < 192) acc[i] = 0.f;  // lam_acc[64], mask_acc[64], loglik_sum[64]
  flags[i] = 0;               // 64 batches x 16 ints (64B padded)
}

// ---------------------------------------------------------------------------
// Sequential CT-LSTM scan, 4 blocks per batch, 448 threads, 1 z-row/thread.
// Round 3-8 post-mortem: the scan is WEIGHT-BYTE-STREAMING bound (~40GB/s/CU
// empirical global-load rate; 229KB fp16/CU/step = the flat 5.7us/step).
// Register pinning (r3-7) and LDS residency (r8) both failed. This round:
// fp8-e4m3 weights (114.7KB/CU/step) with per-row scale; decode is ~9 bit-ops
// per 4 weights into f16x2 for v_dot2 (e4m3->f16 exact modulo 2^8, folded
// into sc_r, applied once per z row).
// Per step: local 448-row z-slice -> global z exchange with one flag
// handshake (agent atomics, parity double-buffer; relaxed polls + single
// acquire fence) -> redundant elementwise recurrence (c/cb in regs, h in
// LDS). Role 0 stores the packed state.
__global__ void
__attribute__((amdgpu_flat_work_group_size(448, 448)))
__attribute__((amdgpu_waves_per_eu(1, 2)))
k_scan(
    const int* __restrict__ event, const float* __restrict__ dtime,
    const float* __restrict__ EW, const unsigned* __restrict__ wq,
    const float* __restrict__ sc,
    float* __restrict__ zx, int* __restrict__ flags,
    uint2* __restrict__ state) {
  const int x = blockIdx.x;
  // co-locate a batch's 4 blocks on one XCD (assuming xcd = blockIdx % 8);
  // correctness does not depend on this mapping, only L2 locality.
  const int xcd = x & 7, q = x >> 3;
  const int b = xcd * 8 + (q >> 2);
  const int role = q & 3;
  const int tid = threadIdx.x;
  const int row = role * 448 + tid;

  __shared__ float4 h4[Hn / 8];      // 256 halves of h
  __shared__ int    ev_s[TP2n];
  __shared__ float  dt_s[TP2n];

  const uint4* wp = reinterpret_cast<const uint4*>(wq) + (size_t)row * 16;
  const float  sc_r = sc[row];

  for (int i = tid; i < TP2n; i += 448) {
    ev_s[i] = event[b * TP2n + i];
    dt_s[i] = dtime[b * TP2n + i];
  }
  if (tid < Hn / 8) h4[tid] = make_float4(0.f, 0.f, 0.f, 0.f);
  __syncthreads();

  float c_r = 0.f, cb_r = 0.f;      // replicated recurrent state (tid<256)
  int* flg = flags + b * 16;
  float ew_pf = EW[(size_t)ev_s[0] * H7n + row];

  for (int t = 0; t < Tn; ++t) {
    const int par = t & 1;
    float ewc = ew_pf;
    ew_pf = EW[(size_t)ev_s[t + 1] * H7n + row];  // prefetch next step

    // ---- z for this thread's row: fp8 weights, 4 independent dot chains ----
    float a0 = 0.f, a1 = 0.f, a2 = 0.f, a3 = 0.f;
#pragma unroll
    for (int i = 0; i < 16; ++i) {
      uint4 ww = wp[i];                // 16 fp8 weights (cols 16i..16i+15)
      float4 hA = h4[2 * i];           // uniform-address broadcast reads
      float4 hB = h4[2 * i + 1];
      dec_dot2(ww.x, hA.x, hA.y, a0, a1);
      dec_dot2(ww.y, hA.z, hA.w, a2, a3);
      dec_dot2(ww.z, hB.x, hB.y, a0, a1);
      dec_dot2(ww.w, hB.z, hB.w, a2, a3);
    }
    float z = ewc + sc_r * ((a0 + a1) + (a2 + a3));

    // ---- exchange: write slice, one flag handshake ----
    float* zb = zx + ((size_t)b * 2 + par) * H7n;
    __hip_atomic_store(zb + row, z, __ATOMIC_RELAXED, __HIP_MEMORY_SCOPE_AGENT);
    __syncthreads();                 // drains vmcnt: all block stores visible
    if (tid == 0)
      __hip_atomic_store(flg + role, t + 1, __ATOMIC_RELEASE,
                         __HIP_MEMORY_SCOPE_AGENT);
    if (tid < 4) {
      // relaxed polls (no per-poll L1 invalidate), single acquire fence after
      while (__hip_atomic_load(flg + tid, __ATOMIC_RELAXED,
                               __HIP_MEMORY_SCOPE_AGENT) <= t) {}
      __builtin_amdgcn_fence(__ATOMIC_ACQUIRE, "agent");
    }
    __syncthreads();

    // ---- elementwise recurrence, replicated (threads 0..255) ----
    if (tid < Hn) {
      const int j = tid;
      float zg[7];
#pragma unroll
      for (int g = 0; g < 7; ++g)
        zg[g] = __hip_atomic_load(zb + g * Hn + j, __ATOMIC_RELAXED,
                                  __HIP_MEMORY_SCOPE_AGENT);
      float gi  = sigmf(zg[0]);
      float gf  = sigmf(zg[1]);
      float go  = sigmf(zg[2]);
      float zc  = tanhfast(zg[3]);
      float gib = sigmf(zg[4]);
      float gfb = sigmf(zg[5]);
      float gd  = softplusf(zg[6]);
      float dt  = dt_s[t + 1];
      float ci  = gf * c_r + gi * zc;
      float cbi = gfb * cb_r + gib * zc;
      float cn  = cbi + (ci - cbi) * __expf(-gd * dt);
      float hn  = go * tanhfast(cn);
      c_r = cn; cb_r = cbi;
      reinterpret_cast<__half*>(h4)[j] = __float2half(hn);
      if (role == 0) {
        f16x2 p0; p0[0] = (_Float16)ci; p0[1] = (_Float16)cbi;
        f16x2 p1; p1[0] = (_Float16)gd; p1[1] = (_Float16)go;
        uint2 o;
        o.x = __builtin_bit_cast(unsigned, p0);
        o.y = __builtin_bit_cast(unsigned, p1);
        state[((size_t)b * Tn + t) * Hn + j] = o;
      }
    }
    __syncthreads();
  }
}

// ---------------------------------------------------------------------------
// log_lam_tgt, fully parallel: one wave per (b,t). Recomputes h_next from the
// packed state (same formula as sampling with dt = dtime[t+1]).
__global__ __launch_bounds__(256) void k_post(
    const uint2* __restrict__ state, const int* __restrict__ event,
    const float* __restrict__ dtime, const float* __restrict__ Wl,
    float* __restrict__ loglik_sum) {
  const int wid = blockIdx.x * 4 + (threadIdx.x >> 6);  // 0..65471
  const int lane = threadIdx.x & 63;
  const int b = wid / Tn;
  const int t = wid - b * Tn;
  const int tgt = event[b * TP2n + t + 1];
  if (tgt >= Kn) return;                                 // wave-uniform
  const float dtv = dtime[b * TP2n + t + 1];
  const uint2* srow = state + (size_t)wid * Hn;
  uint4 sA = *reinterpret_cast<const uint4*>(srow + lane * 4);
  uint4 sB = *reinterpret_cast<const uint4*>(srow + lane * 4 + 2);
  float4 wl = *reinterpret_cast<const float4*>(Wl + tgt * Hn + lane * 4);
  float h[4];
#pragma unroll
  for (int qq = 0; qq < 4; ++qq) {
    unsigned lo = (qq == 0) ? sA.x : (qq == 1) ? sA.z : (qq == 2) ? sB.x : sB.z;
    unsigned hi = (qq == 0) ? sA.y : (qq == 1) ? sA.w : (qq == 2) ? sB.y : sB.w;
    f16x2 p0 = u2h(lo), p1 = u2h(hi);
    float c = p0[0], cb = p0[1], gd = p1[0], go = p1[1];
    float cs = cb + (c - cb) * __expf(-gd * dtv);
    h[qq] = go * tanhfast(cs);
  }
  float d = h[0] * wl.x + h[1] * wl.y + h[2] * wl.z + h[3] * wl.w;
#pragma unroll
  for (int off = 32; off; off >>= 1) d += __shfl_down(d, off);
  if (lane == 0) atomicAdd(&loglik_sum[b], __logf(softplusf(d) + EPSF));
}

// ---------------------------------------------------------------------------
// Sampling: 1024 blocks (16/batch, 64 samples each) x 128 threads; thread k
// holds Wl row k in registers. Packed-state gather (one uint4/thread),
// next-sample prefetch.
__global__ __launch_bounds__(128) void k_samp(
    const uint2* __restrict__ state, const float* __restrict__ Wl,
    const int* __restrict__ sidx, const float* __restrict__ sdt,
    const float* __restrict__ smask,
    float* __restrict__ lam_acc, float* __restrict__ mask_acc) {
  const int blk = blockIdx.x;
  const int b = blk >> 4;
  const int base = (b << 10) + (blk & 15) * 64;
  const int tid = threadIdx.x;

  f16x2 wr[128];
  {
    const float* wrow = Wl + tid * Hn;
#pragma unroll
    for (int i = 0; i < 128; ++i) {
      f16x2 v; v[0] = (_Float16)wrow[2 * i]; v[1] = (_Float16)wrow[2 * i + 1];
      wr[i] = v;
    }
  }
  __shared__ float4 hy4[Hn / 8];
  __shared__ float  red[2];
  float accl = 0.f, accm = 0.f;

  int   row = sidx[base];
  float dtv = sdt[base];
  float mk  = smask[base];
  uint4 st = *reinterpret_cast<const uint4*>(state + (size_t)row * Hn + 2 * tid);

  for (int s = 0; s < 64; ++s) {
    f16x2 p0 = u2h(st.x), p1 = u2h(st.y);
    f16x2 q0 = u2h(st.z), q1 = u2h(st.w);
    float cs0 = (float)p0[1] + ((float)p0[0] - (float)p0[1]) * __expf(-(float)p1[0] * dtv);
    float cs1 = (float)q0[1] + ((float)q0[0] - (float)q0[1]) * __expf(-(float)q1[0] * dtv);
    f16x2 hp;
    hp[0] = (_Float16)((float)p1[1] * tanhfast(cs0));
    hp[1] = (_Float16)((float)q1[1] * tanhfast(cs1));
    reinterpret_cast<unsigned*>(hy4)[tid] = __builtin_bit_cast(unsigned, hp);

    uint4 st_n = st; float dt_n = dtv, mk_n = mk;
    if (s < 63) {
      int sg = base + s + 1;
      int r2 = sidx[sg];
      dt_n = sdt[sg];
      mk_n = smask[sg];
      st_n = *reinterpret_cast<const uint4*>(state + (size_t)r2 * Hn + 2 * tid);
    }
    __syncthreads();

    float d = 0.f;
#pragma unroll
    for (int q = 0; q < 32; ++q) {
      float4 hq = hy4[q];
      d = fdot2f(wr[4 * q + 0], f2h(hq.x), d);
      d = fdot2f(wr[4 * q + 1], f2h(hq.y), d);
      d = fdot2f(wr[4 * q + 2], f2h(hq.z), d);
      d = fdot2f(wr[4 * q + 3], f2h(hq.w), d);
    }
    float lam = softplusf(d);
#pragma unroll
    for (int off = 32; off; off >>= 1) lam += __shfl_down(lam, off);
    if ((tid & 63) == 0) red[tid >> 6] = lam;
    __syncthreads();
    if (tid == 0) {
      accl += (red[0] + red[1]) * mk;
      accm += mk;
    }
    st = st_n; dtv = dt_n; mk = mk_n;
  }
  if (tid == 0) {
    atomicAdd(&lam_acc[b], accl);
    atomicAdd(&mask_acc[b], accm);
  }
}

// ---------------------------------------------------------------------------
__global__ void k_final(const float* __restrict__ loglik_sum,
                        const float* __restrict__ lam_acc,
                        const float* __restrict__ mask_acc,
                        const float* __restrict__ duration,
                        float* __restrict__ out) {
  int b = threadIdx.x;
  if (b < Bn) out[b] = loglik_sum[b] - (lam_acc[b] / mask_acc[b]) * duration[b];
}

// ---------------------------------------------------------------------------
extern "C" void kernel_launch(void* const* d_in, const int* in_sizes, int n_in,
                              void* d_out, int out_size, void* d_ws, size_t ws_size,
                              hipStream_t stream) {
  const int*   event    = (const int*)d_in[0];
  const float* dtime    = (const float*)d_in[1];
  const float* duration = (const float*)d_in[3];
  const float* sdt      = (const float*)d_in[4];
  const int*   sidx     = (const int*)d_in[5];
  const float* smask    = (const float*)d_in[6];
  const float* Emb      = (const float*)d_in[7];
  const float* W        = (const float*)d_in[8];
  const float* bv       = (const float*)d_in[9];
  const float* Wl       = (const float*)d_in[10];

  char* ws = (char*)d_ws;
  // layout: EW(0.94MB)@0 | wq(448KB)@1MB | acc(768B)+flags(4KB)+sc(7KB)@2MB |
  //         zx(0.92MB)@3MB | packed state(134MB)@4MB
  float*    EW         = (float*)(ws + 0);
  unsigned* wq         = (unsigned*)(ws + (1u << 20));
  float*    lam_acc    = (float*)(ws + (2u << 20));
  float*    mask_acc   = lam_acc + 64;
  float*    loglik_sum = lam_acc + 128;
  int*      flags      = (int*)(ws + (2u << 20) + 4096);
  float*    sc         = (float*)(ws + (2u << 20) + 16384);
  float*    zx         = (float*)(ws + (3u << 20));
  uint2*    state      = (uint2*)(ws + (4u << 20));

  k_ew<<<dim3(NEn), dim3(256), 0, stream>>>(Emb, W, bv, EW);
  k_wq<<<dim3(H7n), dim3(64), 0, stream>>>(W, wq, sc);
  k_init<<<dim3(1), dim3(1024), 0, stream>>>(lam_acc, flags);
  k_scan<<<dim3(256), dim3(448), 0, stream>>>(event, dtime, EW, wq, sc, zx,
                                              flags, state);
  k_post<<<dim3(16368), dim3(256), 0, stream>>>(state, event, dtime, Wl,
                                                loglik_sum);
  k_samp<<<dim3(1024), dim3(128), 0, stream>>>(state, Wl, sidx, sdt, smask,
                                               lam_acc, mask_acc);
  k_final<<<dim3(1), dim3(64), 0, stream>>>(loglik_sum, lam_acc, mask_acc,
                                            duration, (float*)d_out);
}